// Round 5
// baseline (399.581 us; speedup 1.0000x reference)
//
#include <hip/hip_runtime.h>

// ExpFlow: scaling-and-squaring exponentiation of a velocity field.
// x: [N=2, C=3, 128^3] f32. u0 = x/32; 5x: u <- u + warp(u, id+u).
//
// R5: AoS padded to 4 channels ([N,D,H,W,4]) so every access is a 16B-aligned
// dwordx4 (R4's unpadded AoS used under-aligned f32x4 derefs = UB, and failed
// post-timing revalidation). Two AoS4 ping-pong buffers live in d_ws (134 MB);
// if ws_size is too small, fall back to the R3-proven SoA chain. d_out is
// written exactly once (step 5).

namespace {
constexpr int kD = 128, kH = 128, kW = 128, kN = 2, kC = 3;
constexpr int kPlane = kD * kH * kW;        // 2^21
constexpr int kVol  = kC * kPlane;          // SoA per-batch floats
constexpr int kVol4 = 4 * kPlane;           // AoS4 per-batch floats
constexpr int kTotalVox = kN * kPlane;
constexpr float kScale0 = 1.0f / 32.0f;
}

typedef float f32x2 __attribute__((ext_vector_type(2)));
typedef float f32x4 __attribute__((ext_vector_type(4)));

enum Layout { SoA = 0, AoS4 = 1 };

template <int SRC, int DST, bool SCALED>
__global__ __launch_bounds__(256) void step_kernel(const float* __restrict__ u,
                                                   float* __restrict__ out) {
    int tid = blockIdx.x * 256 + threadIdx.x;       // < kTotalVox/2
    int n  = tid >> 20;                              // 2^20 thread-pairs per batch
    int rr = (tid & ((kPlane / 2) - 1)) << 1;        // even voxel index in plane
    int w = rr & 127;
    int h = (rr >> 7) & 127;
    int d = rr >> 14;

    const float* __restrict__ ub =
        u + (size_t)n * (SRC == AoS4 ? kVol4 : kVol);

    // ---- base velocity for voxels (w, w+1) ----
    float base[2][3];
    if (SRC == AoS4) {
        f32x4 b0 = *(const f32x4*)(ub + (size_t)rr * 4);        // 16B aligned
        f32x4 b1 = *(const f32x4*)(ub + (size_t)(rr + 1) * 4);
        base[0][0] = b0.x; base[0][1] = b0.y; base[0][2] = b0.z;
        base[1][0] = b1.x; base[1][1] = b1.y; base[1][2] = b1.z;
    } else {
        f32x2 bx = *(const f32x2*)(ub + rr);
        f32x2 by = *(const f32x2*)(ub + kPlane + rr);
        f32x2 bz = *(const f32x2*)(ub + 2 * kPlane + rr);
        base[0][0] = bx.x; base[1][0] = bx.y;
        base[0][1] = by.x; base[1][1] = by.y;
        base[0][2] = bz.x; base[1][2] = bz.y;
    }
    if (SCALED) {
        #pragma unroll
        for (int j = 0; j < 2; ++j)
            #pragma unroll
            for (int c = 0; c < 3; ++c) base[j][c] *= kScale0;
    }

    // ---- cube offsets + weights (border clamp folded into low corner) ----
    int   o[2];
    float wxa[2], wya[2], wza[2];
    #pragma unroll
    for (int j = 0; j < 2; ++j) {
        float px = fminf(fmaxf((float)(w + j) + base[j][0] * 63.5f, 0.0f), 127.0f);
        float py = fminf(fmaxf((float)h       + base[j][1] * 63.5f, 0.0f), 127.0f);
        float pz = fminf(fmaxf((float)d       + base[j][2] * 63.5f, 0.0f), 127.0f);
        int x0 = min((int)floorf(px), 126);
        int y0 = min((int)floorf(py), 126);
        int z0 = min((int)floorf(pz), 126);
        wxa[j] = px - (float)x0;
        wya[j] = py - (float)y0;
        wza[j] = pz - (float)z0;
        o[j] = (z0 << 14) + (y0 << 7) + x0;
    }
    const int rowoff[4] = {0, 128, 16384, 16512};  // (z0,y0)(z0,y1)(z1,y0)(z1,y1)

    // ---- gather + trilinear (x, then y, then z — reference ordering) ----
    float res[2][3];
    #pragma unroll
    for (int j = 0; j < 2; ++j) {
        float wx = wxa[j], wy = wya[j], wz = wza[j];
        float omx = 1.0f - wx, omy = 1.0f - wy, omz = 1.0f - wz;
        float cy[4][3];   // per row r: x-lerped value per channel
        if (SRC == AoS4) {
            #pragma unroll
            for (int r = 0; r < 4; ++r) {
                f32x4 v0 = *(const f32x4*)(ub + (size_t)(o[j] + rowoff[r]) * 4);
                f32x4 v1 = *(const f32x4*)(ub + (size_t)(o[j] + rowoff[r] + 1) * 4);
                if (SCALED) { v0 *= kScale0; v1 *= kScale0; }
                cy[r][0] = v0.x * omx + v1.x * wx;
                cy[r][1] = v0.y * omx + v1.y * wx;
                cy[r][2] = v0.z * omx + v1.z * wx;
            }
        } else {
            #pragma unroll
            for (int c = 0; c < 3; ++c) {
                const float* __restrict__ up = ub + c * kPlane;
                #pragma unroll
                for (int r = 0; r < 4; ++r) {
                    f32x2 v = *(const f32x2*)(up + o[j] + rowoff[r]);  // 8B aligned? o odd -> 4B; keep scalar pair
                    float a = v.x, b = v.y;
                    if (SCALED) { a *= kScale0; b *= kScale0; }
                    cy[r][c] = a * omx + b * wx;
                }
            }
        }
        #pragma unroll
        for (int c = 0; c < 3; ++c) {
            float c0 = cy[0][c] * omy + cy[1][c] * wy;
            float c1 = cy[2][c] * omy + cy[3][c] * wy;
            res[j][c] = base[j][c] + (c0 * omz + c1 * wz);
        }
    }

    // ---- store ----
    if (DST == AoS4) {
        float* __restrict__ ob = out + (size_t)n * kVol4;
        *(f32x4*)(ob + (size_t)rr * 4)       = f32x4{res[0][0], res[0][1], res[0][2], 0.0f};
        *(f32x4*)(ob + (size_t)(rr + 1) * 4) = f32x4{res[1][0], res[1][1], res[1][2], 0.0f};
    } else {
        float* __restrict__ ob = out + (size_t)n * kVol;
        *(f32x2*)(ob + rr)              = f32x2{res[0][0], res[1][0]};
        *(f32x2*)(ob + kPlane + rr)     = f32x2{res[0][1], res[1][1]};
        *(f32x2*)(ob + 2 * kPlane + rr) = f32x2{res[0][2], res[1][2]};
    }
}

extern "C" void kernel_launch(void* const* d_in, const int* in_sizes, int n_in,
                              void* d_out, int out_size, void* d_ws, size_t ws_size,
                              hipStream_t stream) {
    const float* x = (const float*)d_in[0];
    float* out = (float*)d_out;
    float* ws  = (float*)d_ws;

    const int grd = kTotalVox / (256 * 2);
    const size_t need = (size_t)2 * kN * kVol4 * sizeof(float);  // 134,217,728 B

    if (ws_size >= need) {
        float* A = ws;
        float* B = ws + (size_t)kN * kVol4;
        step_kernel<SoA,  AoS4, true ><<<grd, 256, 0, stream>>>(x, A);   // s1
        step_kernel<AoS4, AoS4, false><<<grd, 256, 0, stream>>>(A, B);   // s2
        step_kernel<AoS4, AoS4, false><<<grd, 256, 0, stream>>>(B, A);   // s3
        step_kernel<AoS4, AoS4, false><<<grd, 256, 0, stream>>>(A, B);   // s4
        step_kernel<AoS4, SoA,  false><<<grd, 256, 0, stream>>>(B, out); // s5 -> d_out
    } else {
        // Fallback: R3-proven SoA chain (passes full harness at 333 us).
        step_kernel<SoA, SoA, true ><<<grd, 256, 0, stream>>>(x,   out);
        step_kernel<SoA, SoA, false><<<grd, 256, 0, stream>>>(out, ws);
        step_kernel<SoA, SoA, false><<<grd, 256, 0, stream>>>(ws,  out);
        step_kernel<SoA, SoA, false><<<grd, 256, 0, stream>>>(out, ws);
        step_kernel<SoA, SoA, false><<<grd, 256, 0, stream>>>(ws,  out);
    }
}

// Round 7
// 318.346 us; speedup vs baseline: 1.2552x; 1.2552x over previous
//
#include <hip/hip_runtime.h>

// ExpFlow: scaling-and-squaring exponentiation of a velocity field.
// x: [N=2, C=3, 128^3] f32. u0 = x/32; 5x: u <- u + warp(u, id+u).
// SoA [N,3,D,H,W] f32 end-to-end (R3-proven numerics).
//
// R7 = R6 swizzle with the ping-pong parity bug fixed: R6 left the step-5
// result in ws (d_out held step 4). Now two SoA buffers A,B live in d_ws
// (ws_size >= 134 MB, proven in R5) and d_out is written exactly once (s5).
//
// Swizzle theory: dur tracked hbm_bytes at a flat ~1.6 TB/s in R1-R5 (random
// gather lines mixed into the stream kill memory efficiency). blockIdx%8 is
// the HW round-robin XCD assignment; XCD j sweeps contiguous 16-d-plane slabs
// w-major so its compulsory fetch is sequential and gathers hit a ~2.7 MB
// moving window (< 4 MB per-XCD L2).

namespace {
constexpr int kD = 128, kH = 128, kW = 128, kN = 2, kC = 3;
constexpr int kPlane = kD * kH * kW;        // 2^21
constexpr int kVol   = kC * kPlane;
constexpr int kTotalVox   = kN * kPlane;
constexpr int kTotalElems = kN * kVol;      // 12,582,912 floats per buffer
constexpr float kScale0 = 1.0f / 32.0f;
}

typedef float f32x2 __attribute__((ext_vector_type(2)));

template <bool SCALED>
__global__ __launch_bounds__(256) void step_kernel(const float* __restrict__ u,
                                                   float* __restrict__ out) {
    // --- XCD-slab swizzle ---
    // 8192 blocks; b&7 = XCD (HW round-robin); 16 slabs (2 batches x 8
    // d-slabs of 16 planes); XCD j owns slabs j and j+8, swept sequentially.
    int b    = blockIdx.x;
    int xcd  = b & 7;
    int seq  = b >> 3;                    // 0..1023
    int slab = xcd | ((seq >> 9) << 3);   // 0..15
    int n    = slab >> 3;                 // batch
    int dblk = slab & 7;                  // d-slab within batch
    int vo   = ((seq & 511) << 9) | (threadIdx.x << 1);  // within-slab even voxel
    int rr   = (dblk << 18) | vo;         // within-batch plane-linear index

    int w = rr & 127;
    int h = (rr >> 7) & 127;
    int d = rr >> 14;

    const float* __restrict__ ub = u + (size_t)n * kVol;

    // Base velocity for voxels (w, w+1), per channel.
    f32x2 bx = *(const f32x2*)(ub + rr);
    f32x2 by = *(const f32x2*)(ub + kPlane + rr);
    f32x2 bz = *(const f32x2*)(ub + 2 * kPlane + rr);
    if (SCALED) { bx *= kScale0; by *= kScale0; bz *= kScale0; }

    // Cube offsets + weights (border clamp folded into low corner).
    int   o[2];
    float wxa[2], wya[2], wza[2];
    #pragma unroll
    for (int j = 0; j < 2; ++j) {
        float vx = (j == 0) ? bx.x : bx.y;
        float vy = (j == 0) ? by.x : by.y;
        float vz = (j == 0) ? bz.x : bz.y;
        float px = fminf(fmaxf((float)(w + j) + vx * 63.5f, 0.0f), 127.0f);
        float py = fminf(fmaxf((float)h       + vy * 63.5f, 0.0f), 127.0f);
        float pz = fminf(fmaxf((float)d       + vz * 63.5f, 0.0f), 127.0f);
        int x0 = min((int)floorf(px), 126);
        int y0 = min((int)floorf(py), 126);
        int z0 = min((int)floorf(pz), 126);
        wxa[j] = px - (float)x0;
        wya[j] = py - (float)y0;
        wza[j] = pz - (float)z0;
        o[j] = (z0 << 14) + (y0 << 7) + x0;
    }

    // Gather all 24 float2 corner-pairs, then lerp (x, then y, then z).
    const int rowoff[4] = {0, 128, 16384, 16512};
    float res[3][2];
    #pragma unroll
    for (int j = 0; j < 2; ++j) {
        float wx = wxa[j], wy = wya[j], wz = wza[j];
        float omx = 1.0f - wx, omy = 1.0f - wy, omz = 1.0f - wz;
        #pragma unroll
        for (int c = 0; c < 3; ++c) {
            const float* __restrict__ up = ub + c * kPlane;
            f32x2 v00 = *(const f32x2*)(up + o[j] + rowoff[0]);
            f32x2 v01 = *(const f32x2*)(up + o[j] + rowoff[1]);
            f32x2 v10 = *(const f32x2*)(up + o[j] + rowoff[2]);
            f32x2 v11 = *(const f32x2*)(up + o[j] + rowoff[3]);
            if (SCALED) { v00 *= kScale0; v01 *= kScale0; v10 *= kScale0; v11 *= kScale0; }
            float c00 = v00.x * omx + v00.y * wx;
            float c01 = v01.x * omx + v01.y * wx;
            float c10 = v10.x * omx + v10.y * wx;
            float c11 = v11.x * omx + v11.y * wx;
            float c0 = c00 * omy + c01 * wy;
            float c1 = c10 * omy + c11 * wy;
            float s  = c0 * omz + c1 * wz;
            float base = (c == 0) ? ((j == 0) ? bx.x : bx.y)
                       : (c == 1) ? ((j == 0) ? by.x : by.y)
                                  : ((j == 0) ? bz.x : bz.y);
            res[c][j] = base + s;
        }
    }

    float* __restrict__ ob = out + (size_t)n * kVol;
    *(f32x2*)(ob + rr)              = f32x2{res[0][0], res[0][1]};
    *(f32x2*)(ob + kPlane + rr)     = f32x2{res[1][0], res[1][1]};
    *(f32x2*)(ob + 2 * kPlane + rr) = f32x2{res[2][0], res[2][1]};
}

extern "C" void kernel_launch(void* const* d_in, const int* in_sizes, int n_in,
                              void* d_out, int out_size, void* d_ws, size_t ws_size,
                              hipStream_t stream) {
    const float* x = (const float*)d_in[0];
    float* out = (float*)d_out;
    float* ws  = (float*)d_ws;

    const int grd = kTotalVox / (256 * 2);   // 8192 blocks
    const size_t need = (size_t)2 * kTotalElems * sizeof(float);  // 100.7 MB

    if (ws_size >= need) {
        float* A = ws;
        float* B = ws + (size_t)kTotalElems;
        step_kernel<true ><<<grd, 256, 0, stream>>>(x, A);    // s1 (scale fused)
        step_kernel<false><<<grd, 256, 0, stream>>>(A, B);    // s2
        step_kernel<false><<<grd, 256, 0, stream>>>(B, A);    // s3
        step_kernel<false><<<grd, 256, 0, stream>>>(A, B);    // s4
        step_kernel<false><<<grd, 256, 0, stream>>>(B, out);  // s5 -> d_out (once)
    } else {
        // R3-parity fallback: x->out->ws->out->ws->out.
        step_kernel<true ><<<grd, 256, 0, stream>>>(x,   out);
        step_kernel<false><<<grd, 256, 0, stream>>>(out, ws);
        step_kernel<false><<<grd, 256, 0, stream>>>(ws,  out);
        step_kernel<false><<<grd, 256, 0, stream>>>(out, ws);
        step_kernel<false><<<grd, 256, 0, stream>>>(ws,  out);
    }
}